// Round 7
// baseline (423.541 us; speedup 1.0000x reference)
//
#include <hip/hip_runtime.h>

#define NCLS 19
#define HW (512 * 512)
#define NPIX (8 * HW)
#define TILE 512                  // pixels per block; 512 blocks/image (never straddles)
#define NBLK (NPIX / TILE)        // 4096 blocks
#define NTHR 512                  // 8 waves/block; x4 blocks/CU = 32 waves/CU
#define CHUNKS (NCLS * TILE / 4)  // 16B chunks staged per block = 2432

// ws layout: float partials[2*NBLK] (32 KB) | uint counter @ byte 32768
#define CTR_OFF 32768

__global__ __launch_bounds__(NTHR, 8) void lms_main_kernel(
    const float* __restrict__ logits, const int* __restrict__ labels,
    float* __restrict__ partials, unsigned int* __restrict__ counter,
    float* __restrict__ out) {
  const float COEFF = 1.0f / 18.0f;  // 1/(C-1)
  const float LAM_HALF = 0.15f;      // 0.3 / 2

  __shared__ float tile[NCLS * TILE];  // 38912 B -> 4 blocks/CU (LDS-limited)

  const int t = threadIdx.x;
  const long pixel0 = (long)blockIdx.x * TILE;
  const int n = blockIdx.x >> 9;              // image (512 blocks per image)
  const int hw0 = (blockIdx.x & 511) * TILE;  // pixel offset within image
  const float* gbase = logits + (size_t)n * NCLS * HW + hw0;
  const int rot = blockIdx.x % NCLS;  // de-phase channel sweep across blocks

  // ---- stage 19 x 512 floats via async global->LDS DMA, 16B chunks ----
  // row is wave-uniform (f>>7 uniform across 64 consecutive f), so LDS dst is
  // wave-uniform base + lane*16 as required by global_load_lds.
#pragma unroll
  for (int f = t; f < CHUNKS; f += NTHR) {
    int fr = f >> 7;    // nominal channel row (f / 128)
    int col = f & 127;  // 16B chunk within row
    int r = fr + rot;
    if (r >= NCLS) r -= NCLS;  // rotated channel row
    const float* g = gbase + (size_t)r * HW + col * 4;
    const __attribute__((address_space(1))) float* g1 =
        (const __attribute__((address_space(1))) float*)(uintptr_t)g;
    __attribute__((address_space(3))) float* l3 =
        (__attribute__((address_space(3))) float*)(uintptr_t)(&tile[r * TILE + col * 4]);
    __builtin_amdgcn_global_load_lds(g1, l3, 16, 0, 0);
  }

  int lb = labels[pixel0 + t];
  int l = (lb != 255) ? lb : 0;

  __syncthreads();  // drains vmcnt incl. global_load_lds DMAs

  // ---- compute: 1 pixel/thread from LDS (stride-1 b32, 2 lanes/bank: free) --
  float s = 0.f, T = 0.f, S = 0.f;
#pragma unroll
  for (int c = 0; c < NCLS; ++c) {
    float v = tile[c * TILE + t];
    float e = __expf(v);
    s += e;
    T += e * v;
    S += v;
  }
  float xl = tile[l * TILE + t];

  float el = __expf(xl);
  float sm = s - el;  // masked partition (exact: exp(NEG)=0 in ref)
  float margin = (T - el * xl) / sm - COEFF * (S - xl);
  float ce = __logf(s) - xl;
  bool valid = (lb != 255);
  float loss = valid ? (ce + LAM_HALF * margin) : 0.f;
  float cnt = valid ? 1.f : 0.f;

  // ---- wave (64) shuffle reduction -> block partial ----
#pragma unroll
  for (int off = 32; off > 0; off >>= 1) {
    loss += __shfl_down(loss, off, 64);
    cnt += __shfl_down(cnt, off, 64);
  }
  __shared__ float sl[8], sc[8];
  __shared__ int lastFlag;
  int wave = t >> 6;
  int lane = t & 63;
  if (lane == 0) {
    sl[wave] = loss;
    sc[wave] = cnt;
  }
  __syncthreads();
  if (t == 0) {
    float L = 0.f, C = 0.f;
#pragma unroll
    for (int w = 0; w < 8; ++w) {
      L += sl[w];
      C += sc[w];
    }
    partials[2 * blockIdx.x] = L;
    partials[2 * blockIdx.x + 1] = C;
    __threadfence();  // make partial visible device-wide before the ticket
    unsigned int old = atomicAdd(counter, 1u);
    lastFlag = (old == NBLK - 1);
  }
  __syncthreads();

  // ---- last block reduces all 4096 partial pairs (rocPRIM pattern) ----
  if (lastFlag) {
    __threadfence();
    float L = 0.f, C = 0.f;
#pragma unroll
    for (int k = 0; k < NBLK / NTHR; ++k) {  // 8 pairs/thread
      float2 pr = ((const float2*)partials)[t + NTHR * k];
      L += pr.x;
      C += pr.y;
    }
#pragma unroll
    for (int off = 32; off > 0; off >>= 1) {
      L += __shfl_down(L, off, 64);
      C += __shfl_down(C, off, 64);
    }
    if (lane == 0) {
      sl[wave] = L;
      sc[wave] = C;
    }
    __syncthreads();
    if (t == 0) {
      float Lt = 0.f, Ct = 0.f;
#pragma unroll
      for (int w = 0; w < 8; ++w) {
        Lt += sl[w];
        Ct += sc[w];
      }
      out[0] = Lt / Ct;
    }
  }
}

extern "C" void kernel_launch(void* const* d_in, const int* in_sizes, int n_in,
                              void* d_out, int out_size, void* d_ws, size_t ws_size,
                              hipStream_t stream) {
  const float* logits = (const float*)d_in[0];
  const int* labels = (const int*)d_in[1];
  float* out = (float*)d_out;
  float* partials = (float*)d_ws;
  unsigned int* counter = (unsigned int*)((char*)d_ws + CTR_OFF);

  hipMemsetAsync(counter, 0, sizeof(unsigned int), stream);
  lms_main_kernel<<<NBLK, NTHR, 0, stream>>>(logits, labels, partials, counter,
                                             out);
}

// Round 8
// 214.102 us; speedup vs baseline: 1.9782x; 1.9782x over previous
//
#include <hip/hip_runtime.h>

#define NCLS 19
#define HW (512 * 512)
#define NPIX (8 * HW)
#define TILE 512                  // pixels per block; 512 blocks/image (never straddles)
#define NBLK (NPIX / TILE)        // 4096 blocks
#define NTHR 512                  // 8 waves/block; x4 blocks/CU = 32 waves/CU
#define CHUNKS (NCLS * TILE / 4)  // 16B chunks staged per block = 2432

__global__ __launch_bounds__(NTHR, 8) void lms_main_kernel(
    const float* __restrict__ logits, const int* __restrict__ labels,
    float* __restrict__ partials) {
  const float COEFF = 1.0f / 18.0f;  // 1/(C-1)
  const float LAM_HALF = 0.15f;      // 0.3 / 2

  __shared__ float tile[NCLS * TILE];  // 38912 B -> 4 blocks/CU (LDS-limited)

  const int t = threadIdx.x;
  const long pixel0 = (long)blockIdx.x * TILE;
  const int n = blockIdx.x >> 9;              // image (512 blocks per image)
  const int hw0 = (blockIdx.x & 511) * TILE;  // pixel offset within image
  const float* gbase = logits + (size_t)n * NCLS * HW + hw0;

  // ---- stage 19 x 512 floats via async global->LDS DMA, 16B chunks ----
  // LDS dst = f*16: provably wave-uniform base + lane*16 (R7's rotated dst
  // broke this proof -> waterfall; keep it linear).
  // aux=2 = CPol NT: non-temporal/no-allocate — data is single-use streaming.
#pragma unroll
  for (int f = t; f < CHUNKS; f += NTHR) {
    int r = f >> 7;     // channel row (f / 128)
    int col = f & 127;  // 16B chunk within row
    const float* g = gbase + (size_t)r * HW + col * 4;
    const __attribute__((address_space(1))) float* g1 =
        (const __attribute__((address_space(1))) float*)(uintptr_t)g;
    __attribute__((address_space(3))) float* l3 =
        (__attribute__((address_space(3))) float*)(uintptr_t)(&tile[f * 4]);
    __builtin_amdgcn_global_load_lds(g1, l3, 16, 0, 2);
  }

  int lb = labels[pixel0 + t];
  int l = (lb != 255) ? lb : 0;

  __syncthreads();  // drains vmcnt incl. global_load_lds DMAs

  // ---- compute: 1 pixel/thread from LDS (stride-1 b32, 2 lanes/bank: free) --
  float s = 0.f, T = 0.f, S = 0.f;
#pragma unroll
  for (int c = 0; c < NCLS; ++c) {
    float v = tile[c * TILE + t];
    float e = __expf(v);
    s += e;
    T += e * v;
    S += v;
  }
  float xl = tile[l * TILE + t];

  float el = __expf(xl);
  float sm = s - el;  // masked partition (exact: exp(NEG)=0 in ref)
  float margin = (T - el * xl) / sm - COEFF * (S - xl);
  float ce = __logf(s) - xl;
  bool valid = (lb != 255);
  float loss = valid ? (ce + LAM_HALF * margin) : 0.f;
  float cnt = valid ? 1.f : 0.f;

  // ---- wave (64) shuffle reduction -> block -> per-block partial pair ----
#pragma unroll
  for (int off = 32; off > 0; off >>= 1) {
    loss += __shfl_down(loss, off, 64);
    cnt += __shfl_down(cnt, off, 64);
  }
  __shared__ float sl[8], sc[8];
  int wave = t >> 6;
  int lane = t & 63;
  if (lane == 0) {
    sl[wave] = loss;
    sc[wave] = cnt;
  }
  __syncthreads();
  if (t == 0) {
    float L = 0.f, C = 0.f;
#pragma unroll
    for (int w = 0; w < 8; ++w) {
      L += sl[w];
      C += sc[w];
    }
    partials[2 * blockIdx.x] = L;
    partials[2 * blockIdx.x + 1] = C;
  }
}

__global__ __launch_bounds__(1024) void lms_final_kernel(
    const float* __restrict__ partials, float* __restrict__ out) {
  // 4096 partial pairs; 1024 threads x 4 pairs each
  int t = threadIdx.x;
  float loss = 0.f, cnt = 0.f;
#pragma unroll
  for (int k = 0; k < 4; ++k) {
    float2 pr = ((const float2*)partials)[t + 1024 * k];
    loss += pr.x;
    cnt += pr.y;
  }
#pragma unroll
  for (int off = 32; off > 0; off >>= 1) {
    loss += __shfl_down(loss, off, 64);
    cnt += __shfl_down(cnt, off, 64);
  }
  __shared__ float sl[16], sc[16];
  int wave = t >> 6;
  int lane = t & 63;
  if (lane == 0) {
    sl[wave] = loss;
    sc[wave] = cnt;
  }
  __syncthreads();
  if (t == 0) {
    float L = 0.f, C = 0.f;
#pragma unroll
    for (int w = 0; w < 16; ++w) {
      L += sl[w];
      C += sc[w];
    }
    out[0] = L / C;
  }
}

extern "C" void kernel_launch(void* const* d_in, const int* in_sizes, int n_in,
                              void* d_out, int out_size, void* d_ws, size_t ws_size,
                              hipStream_t stream) {
  const float* logits = (const float*)d_in[0];
  const int* labels = (const int*)d_in[1];
  float* out = (float*)d_out;
  float* partials = (float*)d_ws;  // 4096 x {loss, cnt} = 32 KB

  lms_main_kernel<<<NBLK, NTHR, 0, stream>>>(logits, labels, partials);
  lms_final_kernel<<<1, 1024, 0, stream>>>(partials, out);
}